// Round 6
// baseline (2631.032 us; speedup 1.0000x reference)
//
#include <hip/hip_runtime.h>

#define HH 128
#define TT 1024
#define NFUT 64
#define MB 2
#define NBLK 256
#define NITER (TT + NFUT - 1)  // i=1023 -> out[0], i=1086 -> out[63]

typedef _Float16 half8 __attribute__((ext_vector_type(8)));
typedef float floatx4 __attribute__((ext_vector_type(4)));

#define MFMA16(a, b, c) __builtin_amdgcn_mfma_f32_16x16x32_f16((a), (b), (c), 0, 0, 0)

__device__ __forceinline__ float sigm(float v) {
  return __builtin_amdgcn_rcpf(1.0f + __builtin_amdgcn_exp2f(v * -1.442695040888963f));
}
__device__ __forceinline__ float tanh_f(float v) {
  float a = __builtin_fabsf(v);
  float e = __builtin_amdgcn_exp2f(a * -2.885390081777927f);
  float r = (1.0f - e) * __builtin_amdgcn_rcpf(1.0f + e);
  return __builtin_copysignf(r, v);
}
__device__ __forceinline__ half8 ldw8(const float* __restrict__ p) {
  half8 r;
#pragma unroll
  for (int i = 0; i < 8; ++i) r[i] = (_Float16)p[i];
  return r;
}

// Persistent 2-layer LSTM, 256 WG x 512 thr (8 waves), MB=2 rows/WG.
// Each wave owns units [16w,16w+16) of both cells; 48 named half8 B-frags
// (192 regs) pinned by waves_per_eu(2,2) -> 256-reg budget, no spill (r5).
// ONE barrier per encoder step: phase1(i) | BARRIER | phase2(i)+phase1(i+1).
// Race audit: every same-buffer write/read pair is separated by a barrier
// (h1: w@p1(i) pre-B(i), r@p2(i)/p1(i+1) post-B(i); h2: w@p2(i), r@p2(i+1)
// post-B(i+1); opart: w@p2(i), extra-B, r@p1(i+1), rewritten @p2(i+1)).
// Finalize is in-lane (no shfl): lanes 0-15 hold rows 0,1 in acc[0],acc[1].
// Bias + x*W_ih1 folded into acc init (C-in); rows>=MB get garbage -> never
// read/written, A rows >=MB stay zero in LDS.
__global__
__attribute__((amdgpu_flat_work_group_size(512, 512), amdgpu_waves_per_eu(2, 2)))
void lstm_kernel(
    const float* __restrict__ x,
    const float* __restrict__ W_ih1, const float* __restrict__ b_ih1,
    const float* __restrict__ W_hh1, const float* __restrict__ b_hh1,
    const float* __restrict__ W_ih2, const float* __restrict__ b_ih2,
    const float* __restrict__ W_hh2, const float* __restrict__ b_hh2,
    const float* __restrict__ W_out, const float* __restrict__ b_out,
    float* __restrict__ out)
{
  __shared__ __align__(16) _Float16 h1b[2][2048];  // A-frag order; rows>=MB stay 0
  __shared__ __align__(16) _Float16 h2b[2][2048];
  __shared__ __align__(16) _Float16 xs[TT * MB];   // [t][b]
  __shared__ float opart[8 * MB];

  const int tid = (int)threadIdx.x;
  const int lane = tid & 63;
  const int w = tid >> 6;
  const int jl = lane & 15;
  const int rg = lane >> 4;
  const int j = w * 16 + jl;
  const int b0g = (int)blockIdx.x * MB;

  for (int idx = tid; idx < TT * MB; idx += 512) {
    int t = idx & (TT - 1);
    int bb = idx >> 10;
    xs[t * MB + bb] = (_Float16)x[(b0g + bb) * TT + t];
  }
  for (int idx = tid; idx < 2 * 2048; idx += 512) {
    h1b[idx >> 11][idx & 2047] = (_Float16)0.0f;
    h2b[idx >> 11][idx & 2047] = (_Float16)0.0f;
  }

  // ---- 48 named weight B-fragments: A=W_hh1, H=W_hh2, I=W_ih2 ----
  half8 A00, A01, A02, A03, A10, A11, A12, A13, A20, A21, A22, A23, A30, A31, A32, A33;
  half8 H00, H01, H02, H03, H10, H11, H12, H13, H20, H21, H22, H23, H30, H31, H32, H33;
  half8 I00, I01, I02, I03, I10, I11, I12, I13, I20, I21, I22, I23, I30, I31, I32, I33;
#define LDW(N, Q, P) do { \
    const float* _p = (P) + ((Q) * HH + j) * HH + rg * 8; \
    N##0 = ldw8(_p);      N##1 = ldw8(_p + 32); \
    N##2 = ldw8(_p + 64); N##3 = ldw8(_p + 96); } while (0)
  LDW(A0, 0, W_hh1); LDW(A1, 1, W_hh1); LDW(A2, 2, W_hh1); LDW(A3, 3, W_hh1);
  LDW(H0, 0, W_hh2); LDW(H1, 1, W_hh2); LDW(H2, 2, W_hh2); LDW(H3, 3, W_hh2);
  LDW(I0, 0, W_ih2); LDW(I1, 1, W_ih2); LDW(I2, 2, W_ih2); LDW(I3, 3, W_ih2);

  float bias1[4], bias2[4], wi1[4];
#pragma unroll
  for (int q = 0; q < 4; ++q) {
    bias1[q] = b_ih1[q * HH + j] + b_hh1[q * HH + j];
    bias2[q] = b_ih2[q * HH + j] + b_hh2[q * HH + j];
    wi1[q] = W_ih1[q * HH + j];
  }
  const float wo = W_out[j];
  const float bo = b_out[0];
  // cell states for (unit j, rows 0/1) — valid on lanes 0-15 of each wave
  float c1a = 0.f, c1b = 0.f, c2a = 0.f, c2b = 0.f;

  __syncthreads();

  const int aoff = lane * 8;
  // h LDS slot for (row 0, unit j); row 1 is +8 elements
  const int wb = ((j >> 5) << 9) + (((j >> 3) & 3) << 7) + (j & 7);

#define G1K(KF) do { \
    half8 av = *(const half8*)(&h1b[cur][KF * 512 + aoff]); \
    a0 = MFMA16(av, A0##KF, a0); a1 = MFMA16(av, A1##KF, a1); \
    a2 = MFMA16(av, A2##KF, a2); a3 = MFMA16(av, A3##KF, a3); } while (0)
#define G2K(KF) do { \
    half8 av = *(const half8*)(&h2b[cur][KF * 512 + aoff]); \
    g0 = MFMA16(av, H0##KF, g0); g1 = MFMA16(av, H1##KF, g1); \
    g2 = MFMA16(av, H2##KF, g2); g3 = MFMA16(av, H3##KF, g3); \
    half8 aw = *(const half8*)(&h1b[nxt][KF * 512 + aoff]); \
    g0 = MFMA16(aw, I0##KF, g0); g1 = MFMA16(aw, I1##KF, g1); \
    g2 = MFMA16(aw, I2##KF, g2); g3 = MFMA16(aw, I3##KF, g3); } while (0)

  for (int i = 0; i < NITER; ++i) {
    const int cur = i & 1;
    const int nxt = cur ^ 1;

    // ---- x for this step (uniform on all lanes; LDS broadcast reads) ----
    float x0, x1;
    if (i < TT) {
      x0 = (float)xs[i * MB + 0];
      x1 = (float)xs[i * MB + 1];
    } else {
      float s0 = bo, s1 = bo;
#pragma unroll
      for (int p = 0; p < 8; ++p) {
        s0 += opart[p * MB + 0];
        s1 += opart[p * MB + 1];
      }
      x0 = s0; x1 = s1;
    }

    // ---- phase 1: gates1 = (bias1 + x*wi1) + h1(i-1) @ W_hh1^T ----
    floatx4 a0, a1, a2, a3;
    a0[0] = bias1[0] + x0 * wi1[0]; a0[1] = bias1[0] + x1 * wi1[0]; a0[2] = bias1[0]; a0[3] = bias1[0];
    a1[0] = bias1[1] + x0 * wi1[1]; a1[1] = bias1[1] + x1 * wi1[1]; a1[2] = bias1[1]; a1[3] = bias1[1];
    a2[0] = bias1[2] + x0 * wi1[2]; a2[1] = bias1[2] + x1 * wi1[2]; a2[2] = bias1[2]; a2[3] = bias1[2];
    a3[0] = bias1[3] + x0 * wi1[3]; a3[1] = bias1[3] + x1 * wi1[3]; a3[2] = bias1[3]; a3[3] = bias1[3];
    G1K(0); G1K(1); G1K(2); G1K(3);
    // in-lane finalize: lanes 0-15 hold rows 0,1 in regs 0,1 (others garbage)
    {
      c1a = sigm(a1[0]) * c1a + sigm(a0[0]) * tanh_f(a2[0]);
      c1b = sigm(a1[1]) * c1b + sigm(a0[1]) * tanh_f(a2[1]);
      float h0 = sigm(a3[0]) * tanh_f(c1a);
      float h1 = sigm(a3[1]) * tanh_f(c1b);
      if (lane < 16) {
        h1b[nxt][wb] = (_Float16)h0;
        h1b[nxt][wb + 8] = (_Float16)h1;
      }
    }
    __syncthreads();  // the ONE barrier: publishes h1(i)

    // ---- phase 2: gates2 = bias2 + h2(i-1)@W_hh2^T + h1(i)@W_ih2^T ----
    floatx4 g0, g1, g2, g3;
    g0[0] = bias2[0]; g0[1] = bias2[0]; g0[2] = bias2[0]; g0[3] = bias2[0];
    g1[0] = bias2[1]; g1[1] = bias2[1]; g1[2] = bias2[1]; g1[3] = bias2[1];
    g2[0] = bias2[2]; g2[1] = bias2[2]; g2[2] = bias2[2]; g2[3] = bias2[2];
    g3[0] = bias2[3]; g3[1] = bias2[3]; g3[2] = bias2[3]; g3[3] = bias2[3];
    G2K(0); G2K(1); G2K(2); G2K(3);
    {
      c2a = sigm(g1[0]) * c2a + sigm(g0[0]) * tanh_f(g2[0]);
      c2b = sigm(g1[1]) * c2b + sigm(g0[1]) * tanh_f(g2[1]);
      float h0 = sigm(g3[0]) * tanh_f(c2a);
      float h1 = sigm(g3[1]) * tanh_f(c2b);
      if (lane < 16) {
        h2b[nxt][wb] = (_Float16)h0;
        h2b[nxt][wb + 8] = (_Float16)h1;
      }
      if (i >= TT - 1) {
        // out-projection partials over this wave's 16 units (valid lanes 0-15;
        // xor group {1,2,4,8} stays closed within lanes 0-15)
        float p0 = h0 * wo, p1 = h1 * wo;
        p0 += __shfl_xor(p0, 1); p1 += __shfl_xor(p1, 1);
        p0 += __shfl_xor(p0, 2); p1 += __shfl_xor(p1, 2);
        p0 += __shfl_xor(p0, 4); p1 += __shfl_xor(p1, 4);
        p0 += __shfl_xor(p0, 8); p1 += __shfl_xor(p1, 8);
        if (lane == 0) {
          opart[w * MB + 0] = p0;
          opart[w * MB + 1] = p1;
        }
      }
    }

    if (i >= TT - 1) {
      __syncthreads();  // publish opart (future feedback + out write)
      if (w == 0 && lane < MB) {
        float s = bo;
#pragma unroll
        for (int p = 0; p < 8; ++p) s += opart[p * MB + lane];
        out[(b0g + lane) * NFUT + (i - (TT - 1))] = s;
      }
    }
    // no barrier at loop end for encoder iters: phase2(i) and phase1(i+1)
    // form one barrier-free region -> waves drift, MFMA overlaps finalize.
  }
}

extern "C" void kernel_launch(void* const* d_in, const int* in_sizes, int n_in,
                              void* d_out, int out_size, void* d_ws, size_t ws_size,
                              hipStream_t stream) {
  const float* x     = (const float*)d_in[0];
  const float* W_ih1 = (const float*)d_in[1];
  const float* b_ih1 = (const float*)d_in[2];
  const float* W_hh1 = (const float*)d_in[3];
  const float* b_hh1 = (const float*)d_in[4];
  const float* W_ih2 = (const float*)d_in[5];
  const float* b_ih2 = (const float*)d_in[6];
  const float* W_hh2 = (const float*)d_in[7];
  const float* b_hh2 = (const float*)d_in[8];
  const float* W_out = (const float*)d_in[9];
  const float* b_out = (const float*)d_in[10];
  (void)in_sizes; (void)n_in; (void)out_size; (void)d_ws; (void)ws_size;

  lstm_kernel<<<dim3(NBLK), dim3(512), 0, stream>>>(
      x, W_ih1, b_ih1, W_hh1, b_hh1, W_ih2, b_ih2, W_hh2, b_hh2, W_out, b_out,
      (float*)d_out);
}

// Round 7
// 2626.141 us; speedup vs baseline: 1.0019x; 1.0019x over previous
//
#include <hip/hip_runtime.h>

#define HH 128
#define TT 1024
#define NFUT 64
#define MB 2
#define NBLK 256
#define NITER (TT + NFUT - 1)  // i=1023 -> out[0], i=1086 -> out[63]

typedef _Float16 half8 __attribute__((ext_vector_type(8)));
typedef float floatx4 __attribute__((ext_vector_type(4)));

#define MFMA16(a, b, c) __builtin_amdgcn_mfma_f32_16x16x32_f16((a), (b), (c), 0, 0, 0)

__device__ __forceinline__ float sigm(float v) {
  return __builtin_amdgcn_rcpf(1.0f + __builtin_amdgcn_exp2f(v * -1.442695040888963f));
}
__device__ __forceinline__ float tanh_f(float v) {
  float a = __builtin_fabsf(v);
  float e = __builtin_amdgcn_exp2f(a * -2.885390081777927f);
  float r = (1.0f - e) * __builtin_amdgcn_rcpf(1.0f + e);
  return __builtin_copysignf(r, v);
}
__device__ __forceinline__ half8 ldw8(const float* __restrict__ p) {
  half8 r;
#pragma unroll
  for (int i = 0; i < 8; ++i) r[i] = (_Float16)p[i];
  return r;
}

// Persistent 2-layer LSTM, 256 WG x 512 thr (8 waves), MB=2 rows/WG.
// Each wave owns units [16w,16w+16) of both cells; 48 named half8 B-frags
// (192 regs) pinned by waves_per_eu(2,2).
// ONE barrier per encoder step: { x-read; phase1(i) } BARRIER { phase2(i) }.
// sched_barrier(0) at loop end prevents the scheduler from interleaving
// phase2(i) with phase1(i+1): that interleave made both 16-reg acc sets
// co-live -> 260 > 256 regs -> spill (r6: WRITE_SIZE 26MB, +940us).
// Race audit (1 barrier): h1 w@p1(i) pre-B(i), r@p2(i)/p1(i+1) post-B(i);
// h2 w@p2(i) post-B(i), r@p2(i+1) post-B(i+1); opart w@p2(i), extra future
// barrier before r@x-read(i+1).
// Finalize is in-lane (no shfl): C layout row=(lane>>4)*4+reg, col=lane&15 ->
// lanes 0-15 hold rows 0,1 in acc[0],acc[1]. Bias + x*W_ih1 folded into acc
// init; rows>=MB garbage but their LDS A rows stay zero and are never read.
__global__
__attribute__((amdgpu_flat_work_group_size(512, 512), amdgpu_waves_per_eu(2, 2)))
void lstm_kernel(
    const float* __restrict__ x,
    const float* __restrict__ W_ih1, const float* __restrict__ b_ih1,
    const float* __restrict__ W_hh1, const float* __restrict__ b_hh1,
    const float* __restrict__ W_ih2, const float* __restrict__ b_ih2,
    const float* __restrict__ W_hh2, const float* __restrict__ b_hh2,
    const float* __restrict__ W_out, const float* __restrict__ b_out,
    float* __restrict__ out)
{
  __shared__ __align__(16) _Float16 h1b[2][2048];  // A-frag order; rows>=MB stay 0
  __shared__ __align__(16) _Float16 h2b[2][2048];
  __shared__ __align__(16) _Float16 xs[TT * MB];   // [t][b]
  __shared__ float opart[8 * MB];

  const int tid = (int)threadIdx.x;
  const int lane = tid & 63;
  const int w = tid >> 6;
  const int jl = lane & 15;
  const int rg = lane >> 4;
  const int j = w * 16 + jl;
  const int b0g = (int)blockIdx.x * MB;

  for (int idx = tid; idx < TT * MB; idx += 512) {
    int t = idx & (TT - 1);
    int bb = idx >> 10;
    xs[t * MB + bb] = (_Float16)x[(b0g + bb) * TT + t];
  }
  for (int idx = tid; idx < 2 * 2048; idx += 512) {
    h1b[idx >> 11][idx & 2047] = (_Float16)0.0f;
    h2b[idx >> 11][idx & 2047] = (_Float16)0.0f;
  }

  // ---- 48 named weight B-fragments: A=W_hh1, H=W_hh2, I=W_ih2 ----
  half8 A00, A01, A02, A03, A10, A11, A12, A13, A20, A21, A22, A23, A30, A31, A32, A33;
  half8 H00, H01, H02, H03, H10, H11, H12, H13, H20, H21, H22, H23, H30, H31, H32, H33;
  half8 I00, I01, I02, I03, I10, I11, I12, I13, I20, I21, I22, I23, I30, I31, I32, I33;
#define LDW(N, Q, P) do { \
    const float* _p = (P) + ((Q) * HH + j) * HH + rg * 8; \
    N##0 = ldw8(_p);      N##1 = ldw8(_p + 32); \
    N##2 = ldw8(_p + 64); N##3 = ldw8(_p + 96); } while (0)
  LDW(A0, 0, W_hh1); LDW(A1, 1, W_hh1); LDW(A2, 2, W_hh1); LDW(A3, 3, W_hh1);
  LDW(H0, 0, W_hh2); LDW(H1, 1, W_hh2); LDW(H2, 2, W_hh2); LDW(H3, 3, W_hh2);
  LDW(I0, 0, W_ih2); LDW(I1, 1, W_ih2); LDW(I2, 2, W_ih2); LDW(I3, 3, W_ih2);

  float bias1[4], bias2[4], wi1[4];
#pragma unroll
  for (int q = 0; q < 4; ++q) {
    bias1[q] = b_ih1[q * HH + j] + b_hh1[q * HH + j];
    bias2[q] = b_ih2[q * HH + j] + b_hh2[q * HH + j];
    wi1[q] = W_ih1[q * HH + j];
  }
  const float wo = W_out[j];
  const float bo = b_out[0];
  float c1a = 0.f, c1b = 0.f, c2a = 0.f, c2b = 0.f;  // lanes 0-15 valid

  __syncthreads();

  const int aoff = lane * 8;
  // h LDS slot for (row 0, unit j); row 1 is +8 elements
  const int wb = ((j >> 5) << 9) + (((j >> 3) & 3) << 7) + (j & 7);

#define G1K(KF) do { \
    half8 av = *(const half8*)(&h1b[cur][KF * 512 + aoff]); \
    a0 = MFMA16(av, A0##KF, a0); a1 = MFMA16(av, A1##KF, a1); \
    a2 = MFMA16(av, A2##KF, a2); a3 = MFMA16(av, A3##KF, a3); } while (0)
#define G2K(KF) do { \
    half8 av = *(const half8*)(&h2b[cur][KF * 512 + aoff]); \
    g0 = MFMA16(av, H0##KF, g0); g1 = MFMA16(av, H1##KF, g1); \
    g2 = MFMA16(av, H2##KF, g2); g3 = MFMA16(av, H3##KF, g3); \
    half8 aw = *(const half8*)(&h1b[nxt][KF * 512 + aoff]); \
    g0 = MFMA16(aw, I0##KF, g0); g1 = MFMA16(aw, I1##KF, g1); \
    g2 = MFMA16(aw, I2##KF, g2); g3 = MFMA16(aw, I3##KF, g3); } while (0)

  for (int i = 0; i < NITER; ++i) {
    const int cur = i & 1;
    const int nxt = cur ^ 1;

    // ---- x for this step (uniform; LDS broadcast) ----
    float x0, x1;
    if (i < TT) {
      x0 = (float)xs[i * MB + 0];
      x1 = (float)xs[i * MB + 1];
    } else {
      float s0 = bo, s1 = bo;
#pragma unroll
      for (int p = 0; p < 8; ++p) {
        s0 += opart[p * MB + 0];
        s1 += opart[p * MB + 1];
      }
      x0 = s0; x1 = s1;
    }

    // ---- phase 1: gates1 = (bias1 + x*wi1) + h1(i-1) @ W_hh1^T ----
    floatx4 a0, a1, a2, a3;
    a0[0] = bias1[0] + x0 * wi1[0]; a0[1] = bias1[0] + x1 * wi1[0]; a0[2] = bias1[0]; a0[3] = bias1[0];
    a1[0] = bias1[1] + x0 * wi1[1]; a1[1] = bias1[1] + x1 * wi1[1]; a1[2] = bias1[1]; a1[3] = bias1[1];
    a2[0] = bias1[2] + x0 * wi1[2]; a2[1] = bias1[2] + x1 * wi1[2]; a2[2] = bias1[2]; a2[3] = bias1[2];
    a3[0] = bias1[3] + x0 * wi1[3]; a3[1] = bias1[3] + x1 * wi1[3]; a3[2] = bias1[3]; a3[3] = bias1[3];
    G1K(0); G1K(1); G1K(2); G1K(3);
    {
      c1a = sigm(a1[0]) * c1a + sigm(a0[0]) * tanh_f(a2[0]);
      c1b = sigm(a1[1]) * c1b + sigm(a0[1]) * tanh_f(a2[1]);
      float h0 = sigm(a3[0]) * tanh_f(c1a);
      float h1 = sigm(a3[1]) * tanh_f(c1b);
      if (lane < 16) {
        h1b[nxt][wb] = (_Float16)h0;
        h1b[nxt][wb + 8] = (_Float16)h1;
      }
    }
    __syncthreads();  // the ONE barrier: publishes h1(i) (and h2(i-1))

    // ---- phase 2: gates2 = bias2 + h2(i-1)@W_hh2^T + h1(i)@W_ih2^T ----
    floatx4 g0, g1, g2, g3;
    g0[0] = bias2[0]; g0[1] = bias2[0]; g0[2] = bias2[0]; g0[3] = bias2[0];
    g1[0] = bias2[1]; g1[1] = bias2[1]; g1[2] = bias2[1]; g1[3] = bias2[1];
    g2[0] = bias2[2]; g2[1] = bias2[2]; g2[2] = bias2[2]; g2[3] = bias2[2];
    g3[0] = bias2[3]; g3[1] = bias2[3]; g3[2] = bias2[3]; g3[3] = bias2[3];
    G2K(0); G2K(1); G2K(2); G2K(3);
    {
      c2a = sigm(g1[0]) * c2a + sigm(g0[0]) * tanh_f(g2[0]);
      c2b = sigm(g1[1]) * c2b + sigm(g0[1]) * tanh_f(g2[1]);
      float h0 = sigm(g3[0]) * tanh_f(c2a);
      float h1 = sigm(g3[1]) * tanh_f(c2b);
      if (lane < 16) {
        h2b[nxt][wb] = (_Float16)h0;
        h2b[nxt][wb + 8] = (_Float16)h1;
      }
      if (i >= TT - 1) {
        float p0 = h0 * wo, p1 = h1 * wo;
        p0 += __shfl_xor(p0, 1); p1 += __shfl_xor(p1, 1);
        p0 += __shfl_xor(p0, 2); p1 += __shfl_xor(p1, 2);
        p0 += __shfl_xor(p0, 4); p1 += __shfl_xor(p1, 4);
        p0 += __shfl_xor(p0, 8); p1 += __shfl_xor(p1, 8);
        if (lane == 0) {
          opart[w * MB + 0] = p0;
          opart[w * MB + 1] = p1;
        }
      }
    }

    if (i >= TT - 1) {
      __syncthreads();  // publish opart (future feedback + out write)
      if (w == 0 && lane < MB) {
        float s = bo;
#pragma unroll
        for (int p = 0; p < 8; ++p) s += opart[p * MB + lane];
        out[(b0g + lane) * NFUT + (i - (TT - 1))] = s;
      }
    }
    // Pin the phase boundary: without this the scheduler interleaves
    // phase2(i) with phase1(i+1) -> both acc sets co-live -> spill (r6).
    __builtin_amdgcn_sched_barrier(0);
  }
}

extern "C" void kernel_launch(void* const* d_in, const int* in_sizes, int n_in,
                              void* d_out, int out_size, void* d_ws, size_t ws_size,
                              hipStream_t stream) {
  const float* x     = (const float*)d_in[0];
  const float* W_ih1 = (const float*)d_in[1];
  const float* b_ih1 = (const float*)d_in[2];
  const float* W_hh1 = (const float*)d_in[3];
  const float* b_hh1 = (const float*)d_in[4];
  const float* W_ih2 = (const float*)d_in[5];
  const float* b_ih2 = (const float*)d_in[6];
  const float* W_hh2 = (const float*)d_in[7];
  const float* b_hh2 = (const float*)d_in[8];
  const float* W_out = (const float*)d_in[9];
  const float* b_out = (const float*)d_in[10];
  (void)in_sizes; (void)n_in; (void)out_size; (void)d_ws; (void)ws_size;

  lstm_kernel<<<dim3(NBLK), dim3(512), 0, stream>>>(
      x, W_ih1, b_ih1, W_hh1, b_hh1, W_ih2, b_ih2, W_hh2, b_hh2, W_out, b_out,
      (float*)d_out);
}

// Round 8
// 1522.993 us; speedup vs baseline: 1.7275x; 1.7243x over previous
//
#include <hip/hip_runtime.h>

#define HH 128
#define TT 1024
#define NFUT 64
#define MB 2
#define NBLK 256
#define NITER (TT + NFUT - 1)  // i=1023 -> out[0], i=1086 -> out[63]

typedef _Float16 half8 __attribute__((ext_vector_type(8)));
typedef float floatx4 __attribute__((ext_vector_type(4)));

#define MFMA16(a, b, c) __builtin_amdgcn_mfma_f32_16x16x32_f16((a), (b), (c), 0, 0, 0)

__device__ __forceinline__ float sigm(float v) {
  return __builtin_amdgcn_rcpf(1.0f + __builtin_amdgcn_exp2f(v * -1.442695040888963f));
}
__device__ __forceinline__ float tanh_f(float v) {
  float a = __builtin_fabsf(v);
  float e = __builtin_amdgcn_exp2f(a * -2.885390081777927f);
  float r = (1.0f - e) * __builtin_amdgcn_rcpf(1.0f + e);
  return __builtin_copysignf(r, v);
}
__device__ __forceinline__ half8 ldw8(const float* __restrict__ p) {
  half8 r;
#pragma unroll
  for (int i = 0; i < 8; ++i) r[i] = (_Float16)p[i];
  return r;
}

// Persistent 2-layer LSTM, 256 WG x 512 thr (8 waves), MB=2 rows/WG.
// Each wave owns units [16w,16w+16) of both cells; 48 named half8 B-frags
// (192 regs) pinned by waves_per_eu(2,2) -> 256 combined regs/wave.
//
// CRITICAL (r5 vs r6/r7 lesson): accumulators MUST be zero-initialized.
// Zero-init lets the compiler place them in AGPRs (v_accvgpr_write 0) so the
// MFMA chain lives entirely in AGPR space; folding bias/x into the C-in made
// the accs arch-VGPR-resident -> 128-reg arch file overflow -> 26 MB scratch
// spill and +950us (r6/r7). Bias + x*W_ih1 are added POST-MFMA to scalars.
//
// ONE barrier per encoder step: { x-read; phase1(i) } B { phase2(i) }.
// Race audit: h1 w@p1(i) pre-B(i), r@p2(i)+p1(i+1) post-B(i); h1[cur_i]
// has no readers after B(i) so p1(i+1)'s write is safe; h2 w@p2(i), r@p2(i+1)
// -- all waves finish p2(i) before any enters p2(i+1) (B(i+1) orders it);
// opart w@p2(i), future-only extra barrier before r@x-read(i+1).
// Finalize in-lane (C layout row=(lane>>4)*4+reg, col=lane&15): lanes 0-15
// hold rows 0,1 in acc[0],acc[1]; no shfl repack.
__global__
__attribute__((amdgpu_flat_work_group_size(512, 512), amdgpu_waves_per_eu(2, 2)))
void lstm_kernel(
    const float* __restrict__ x,
    const float* __restrict__ W_ih1, const float* __restrict__ b_ih1,
    const float* __restrict__ W_hh1, const float* __restrict__ b_hh1,
    const float* __restrict__ W_ih2, const float* __restrict__ b_ih2,
    const float* __restrict__ W_hh2, const float* __restrict__ b_hh2,
    const float* __restrict__ W_out, const float* __restrict__ b_out,
    float* __restrict__ out)
{
  __shared__ __align__(16) _Float16 h1b[2][2048];  // A-frag order; rows>=MB stay 0
  __shared__ __align__(16) _Float16 h2b[2][2048];
  __shared__ __align__(16) _Float16 xs[TT * MB];   // [t][b]
  __shared__ float opart[8 * MB];

  const int tid = (int)threadIdx.x;
  const int lane = tid & 63;
  const int w = tid >> 6;
  const int jl = lane & 15;
  const int rg = lane >> 4;
  const int j = w * 16 + jl;
  const int b0g = (int)blockIdx.x * MB;

  for (int idx = tid; idx < TT * MB; idx += 512) {
    int t = idx & (TT - 1);
    int bb = idx >> 10;
    xs[t * MB + bb] = (_Float16)x[(b0g + bb) * TT + t];
  }
  for (int idx = tid; idx < 2 * 2048; idx += 512) {
    h1b[idx >> 11][idx & 2047] = (_Float16)0.0f;
    h2b[idx >> 11][idx & 2047] = (_Float16)0.0f;
  }

  // ---- 48 named weight B-fragments: A=W_hh1, H=W_hh2, I=W_ih2 ----
  half8 A00, A01, A02, A03, A10, A11, A12, A13, A20, A21, A22, A23, A30, A31, A32, A33;
  half8 H00, H01, H02, H03, H10, H11, H12, H13, H20, H21, H22, H23, H30, H31, H32, H33;
  half8 I00, I01, I02, I03, I10, I11, I12, I13, I20, I21, I22, I23, I30, I31, I32, I33;
#define LDW(N, Q, P) do { \
    const float* _p = (P) + ((Q) * HH + j) * HH + rg * 8; \
    N##0 = ldw8(_p);      N##1 = ldw8(_p + 32); \
    N##2 = ldw8(_p + 64); N##3 = ldw8(_p + 96); } while (0)
  LDW(A0, 0, W_hh1); LDW(A1, 1, W_hh1); LDW(A2, 2, W_hh1); LDW(A3, 3, W_hh1);
  LDW(H0, 0, W_hh2); LDW(H1, 1, W_hh2); LDW(H2, 2, W_hh2); LDW(H3, 3, W_hh2);
  LDW(I0, 0, W_ih2); LDW(I1, 1, W_ih2); LDW(I2, 2, W_ih2); LDW(I3, 3, W_ih2);

  float bias1[4], bias2[4], wi1[4];
#pragma unroll
  for (int q = 0; q < 4; ++q) {
    bias1[q] = b_ih1[q * HH + j] + b_hh1[q * HH + j];
    bias2[q] = b_ih2[q * HH + j] + b_hh2[q * HH + j];
    wi1[q] = W_ih1[q * HH + j];
  }
  const float wo = W_out[j];
  const float bo = b_out[0];
  float c1a = 0.f, c1b = 0.f, c2a = 0.f, c2b = 0.f;  // lanes 0-15 meaningful

  __syncthreads();

  const int aoff = lane * 8;
  // h LDS slot for (row 0, unit j); row 1 is +8 elements
  const int wb = ((j >> 5) << 9) + (((j >> 3) & 3) << 7) + (j & 7);

#define G1K(KF) do { \
    half8 av = *(const half8*)(&h1b[cur][KF * 512 + aoff]); \
    a0 = MFMA16(av, A0##KF, a0); a1 = MFMA16(av, A1##KF, a1); \
    a2 = MFMA16(av, A2##KF, a2); a3 = MFMA16(av, A3##KF, a3); } while (0)
#define G2K(KF) do { \
    half8 av = *(const half8*)(&h2b[cur][KF * 512 + aoff]); \
    g0 = MFMA16(av, H0##KF, g0); g1 = MFMA16(av, H1##KF, g1); \
    g2 = MFMA16(av, H2##KF, g2); g3 = MFMA16(av, H3##KF, g3); \
    half8 aw = *(const half8*)(&h1b[nxt][KF * 512 + aoff]); \
    g0 = MFMA16(aw, I0##KF, g0); g1 = MFMA16(aw, I1##KF, g1); \
    g2 = MFMA16(aw, I2##KF, g2); g3 = MFMA16(aw, I3##KF, g3); } while (0)

  for (int i = 0; i < NITER; ++i) {
    const int cur = i & 1;
    const int nxt = cur ^ 1;

    // ---- x for this step (uniform; LDS broadcast reads) ----
    float x0, x1;
    if (i < TT) {
      x0 = (float)xs[i * MB + 0];
      x1 = (float)xs[i * MB + 1];
    } else {
      float s0 = bo, s1 = bo;
#pragma unroll
      for (int p = 0; p < 8; ++p) {
        s0 += opart[p * MB + 0];
        s1 += opart[p * MB + 1];
      }
      x0 = s0; x1 = s1;
    }

    // ---- phase 1: gates1 = h1(i-1) @ W_hh1^T  (zero C-in -> accs in AGPR) ----
    floatx4 a0 = {0.f,0.f,0.f,0.f}, a1 = {0.f,0.f,0.f,0.f};
    floatx4 a2 = {0.f,0.f,0.f,0.f}, a3 = {0.f,0.f,0.f,0.f};
    G1K(0); G1K(1); G1K(2); G1K(3);
    {
      // bias + x*W_ih1 added post-MFMA on scalars (keeps C-in zero)
      float gi0 = a0[0] + x0 * wi1[0] + bias1[0], gi1 = a0[1] + x1 * wi1[0] + bias1[0];
      float gf0 = a1[0] + x0 * wi1[1] + bias1[1], gf1 = a1[1] + x1 * wi1[1] + bias1[1];
      float gg0 = a2[0] + x0 * wi1[2] + bias1[2], gg1 = a2[1] + x1 * wi1[2] + bias1[2];
      float go0 = a3[0] + x0 * wi1[3] + bias1[3], go1 = a3[1] + x1 * wi1[3] + bias1[3];
      c1a = sigm(gf0) * c1a + sigm(gi0) * tanh_f(gg0);
      c1b = sigm(gf1) * c1b + sigm(gi1) * tanh_f(gg1);
      float h0 = sigm(go0) * tanh_f(c1a);
      float h1v = sigm(go1) * tanh_f(c1b);
      if (lane < 16) {
        h1b[nxt][wb] = (_Float16)h0;
        h1b[nxt][wb + 8] = (_Float16)h1v;
      }
    }
    __syncthreads();  // the ONE barrier: publishes h1(i)

    // ---- phase 2: gates2 = h2(i-1)@W_hh2^T + h1(i)@W_ih2^T ----
    floatx4 g0 = {0.f,0.f,0.f,0.f}, g1 = {0.f,0.f,0.f,0.f};
    floatx4 g2 = {0.f,0.f,0.f,0.f}, g3 = {0.f,0.f,0.f,0.f};
    G2K(0); G2K(1); G2K(2); G2K(3);
    {
      float gi0 = g0[0] + bias2[0], gi1 = g0[1] + bias2[0];
      float gf0 = g1[0] + bias2[1], gf1 = g1[1] + bias2[1];
      float gg0 = g2[0] + bias2[2], gg1 = g2[1] + bias2[2];
      float go0 = g3[0] + bias2[3], go1 = g3[1] + bias2[3];
      c2a = sigm(gf0) * c2a + sigm(gi0) * tanh_f(gg0);
      c2b = sigm(gf1) * c2b + sigm(gi1) * tanh_f(gg1);
      float h0 = sigm(go0) * tanh_f(c2a);
      float h1v = sigm(go1) * tanh_f(c2b);
      if (lane < 16) {
        h2b[nxt][wb] = (_Float16)h0;
        h2b[nxt][wb + 8] = (_Float16)h1v;
      }
      if (i >= TT - 1) {
        // projection partials over this wave's 16 units (xor group closed
        // within lanes 0-15; only lanes 0-15 hold valid h)
        float p0 = h0 * wo, p1 = h1v * wo;
        p0 += __shfl_xor(p0, 1); p1 += __shfl_xor(p1, 1);
        p0 += __shfl_xor(p0, 2); p1 += __shfl_xor(p1, 2);
        p0 += __shfl_xor(p0, 4); p1 += __shfl_xor(p1, 4);
        p0 += __shfl_xor(p0, 8); p1 += __shfl_xor(p1, 8);
        if (lane == 0) {
          opart[w * MB + 0] = p0;
          opart[w * MB + 1] = p1;
        }
      }
    }

    if (i >= TT - 1) {
      __syncthreads();  // publish opart (future feedback + out write)
      if (w == 0 && lane < MB) {
        float s = bo;
#pragma unroll
        for (int p = 0; p < 8; ++p) s += opart[p * MB + lane];
        out[(b0g + lane) * NFUT + (i - (TT - 1))] = s;
      }
    }
    // keep phase boundary pinned (cheap insurance against acc co-liveness)
    __builtin_amdgcn_sched_barrier(0);
  }
}

extern "C" void kernel_launch(void* const* d_in, const int* in_sizes, int n_in,
                              void* d_out, int out_size, void* d_ws, size_t ws_size,
                              hipStream_t stream) {
  const float* x     = (const float*)d_in[0];
  const float* W_ih1 = (const float*)d_in[1];
  const float* b_ih1 = (const float*)d_in[2];
  const float* W_hh1 = (const float*)d_in[3];
  const float* b_hh1 = (const float*)d_in[4];
  const float* W_ih2 = (const float*)d_in[5];
  const float* b_ih2 = (const float*)d_in[6];
  const float* W_hh2 = (const float*)d_in[7];
  const float* b_hh2 = (const float*)d_in[8];
  const float* W_out = (const float*)d_in[9];
  const float* b_out = (const float*)d_in[10];
  (void)in_sizes; (void)n_in; (void)out_size; (void)d_ws; (void)ws_size;

  lstm_kernel<<<dim3(NBLK), dim3(512), 0, stream>>>(
      x, W_ih1, b_ih1, W_hh1, b_hh1, W_ih2, b_ih2, W_hh2, b_hh2, W_out, b_out,
      (float*)d_out);
}